// Round 12
// baseline (191.123 us; speedup 1.0000x reference)
//
#include <hip/hip_runtime.h>
#include <hip/hip_bf16.h>
#include <hip/hip_fp16.h>

#define N_NODES 100000
#define N_EDGES 1600000
#define N_GRAPHS 64

#define NB_BKT 256      // node buckets for CSR build
#define NPBKT 391       // nodes per bucket (255*391=99705, last bucket 295)
#define EPB 4096        // edges per bin block
#define NBLK_FEAT ((N_NODES + 255) / 256)            // 391
#define NBLK_BIN ((N_EDGES + EPB - 1) / EPB)         // 391
#define BKT_CAP 7168    // per-bucket rec capacity: mean 6256, sigma 79 -> +11.5 sigma

// ---------------- f16 helpers ----------------

__device__ __forceinline__ __half2 u2h(unsigned int u) {
    return __builtin_bit_cast(__half2, u);
}
__device__ __forceinline__ float2 u2f2(unsigned int u) {
    return __half22float2(u2h(u));
}
__device__ __forceinline__ unsigned int packh2(float a, float b) {
    return __builtin_bit_cast(unsigned int, __float22half2_rn(make_float2(a, b)));
}

// ---------------- prep: feat->f16 rows (blocks [0,391)) + edge binning (blocks [391,782)) ----

__global__ __launch_bounds__(256) void prep(const float* __restrict__ feat,
                                            const int* __restrict__ dst,
                                            const int* __restrict__ src,
                                            uint4* __restrict__ feat16,
                                            int* __restrict__ gcur,
                                            uint2* __restrict__ rec, int n, int E) {
    __shared__ int cnt[NB_BKT];
    __shared__ int lbase[NB_BKT];
    __shared__ int gofs[NB_BKT];
    __shared__ uint2 stage[EPB];  // 32 KB
    int t = threadIdx.x;

    if ((int)blockIdx.x < NBLK_FEAT) {
        __shared__ float sf[256 * 6];
        int b0 = blockIdx.x * 256;
        int c = min(256, n - b0) * 6;
        for (int i = t; i < c; i += 256) sf[i] = feat[(size_t)b0 * 6 + i];
        __syncthreads();
        int v = b0 + t;
        if (v < n) {
            const float* f = sf + t * 6;
            uint4 r;
            r.x = packh2(f[0], f[1]);
            r.y = packh2(f[2], f[3]);
            r.z = packh2(f[4], f[5]);
            r.w = 0u;
            feat16[v] = r;
        }
        return;
    }

    int e0 = (blockIdx.x - NBLK_FEAT) * EPB;
    cnt[t] = 0;
    __syncthreads();
    int myb[16], mypos[16];
    unsigned myd[16], mys[16];
#pragma unroll
    for (int k = 0; k < 16; ++k) {
        int e = e0 + k * 256 + t;
        if (e < E) {
            unsigned d = (unsigned)dst[e];
            int b = (int)(d / (unsigned)NPBKT);
            myd[k] = d;
            mys[k] = (unsigned)src[e];
            myb[k] = b;
            mypos[k] = atomicAdd(&cnt[b], 1);
        } else {
            myb[k] = -1;
        }
    }
    __syncthreads();
    int c = cnt[t];
    int res = (c > 0) ? atomicAdd(&gcur[t], c) : 0;  // reserve range in bucket t
    lbase[t] = c;
    __syncthreads();
    for (int o = 1; o < 256; o <<= 1) {
        int a = (t >= o) ? lbase[t - o] : 0;
        __syncthreads();
        lbase[t] += a;
        __syncthreads();
    }
    lbase[t] -= c;
    gofs[t] = res;
    __syncthreads();
#pragma unroll
    for (int k = 0; k < 16; ++k)
        if (myb[k] >= 0) stage[lbase[myb[k]] + mypos[k]] = make_uint2(myd[k], mys[k]);
    __syncthreads();
    int total = min(EPB, E - e0);
    for (int i = t; i < total; i += 256) {
        int lo = 0, hi = NB_BKT - 1;
        while (lo < hi) {
            int m = (lo + hi + 1) >> 1;
            if (lbase[m] <= i) lo = m; else hi = m - 1;
        }
        rec[(size_t)lo * BKT_CAP + gofs[lo] + (i - lbase[lo])] = stage[i];
    }
}

// ---------------- fill_bucket: one workgroup per bucket ----------------
// Local deg+prefix -> rp; scatter col inside LDS; stream out coalesced.
// Also emits perm[]: bucket-local counting sort of nodes by degree, so layer
// kernels can process degree-uniform waves (kills straggler divergence).

__global__ __launch_bounds__(256) void fill_bucket(const uint2* __restrict__ rec,
                                                   const int* __restrict__ gcur,
                                                   int* __restrict__ rp,
                                                   int* __restrict__ col,
                                                   int* __restrict__ perm, int n) {
    __shared__ int sdeg[512];
    __shared__ int lcur[512];
    __shared__ int sg[256];
    __shared__ int hist[256];
    __shared__ int lcol[8192];
    int p = blockIdx.x, t = threadIdx.x;
    int nbase = p * NPBKT;
    int nn = min(NPBKT, n - nbase);
    int g = gcur[t];
    sg[t] = g;
    __syncthreads();
    for (int o = 1; o < 256; o <<= 1) {
        int a = (t >= o) ? sg[t - o] : 0;
        __syncthreads();
        sg[t] += a;
        __syncthreads();
    }
    int ex = sg[t] - g;
    __syncthreads();
    sg[t] = ex;
    __syncthreads();
    int cbase = sg[p];
    int cnt = gcur[p];
    sdeg[t] = 0;
    sdeg[t + 256] = 0;
    __syncthreads();
    const uint2* r = rec + (size_t)p * BKT_CAP;
    for (int i = t; i < cnt; i += 256) atomicAdd(&sdeg[r[i].x - (unsigned)nbase], 1);
    __syncthreads();
    int c0 = sdeg[t], c1 = sdeg[t + 256];
    for (int o = 1; o < 512; o <<= 1) {
        int a = (t >= o) ? sdeg[t - o] : 0;
        int b = (t + 256 >= o) ? sdeg[t + 256 - o] : 0;
        __syncthreads();
        sdeg[t] += a;
        sdeg[t + 256] += b;
        __syncthreads();
    }
    int ex0 = sdeg[t] - c0, ex1 = sdeg[t + 256] - c1;
    lcur[t] = ex0;
    lcur[t + 256] = ex1;
    if (t < nn) rp[nbase + t] = cbase + ex0;
    if (t + 256 < nn) rp[nbase + t + 256] = cbase + ex1;
    if (p == NB_BKT - 1 && t == 0) rp[n] = cbase + cnt;
    __syncthreads();
    for (int i = t; i < cnt; i += 256) {
        uint2 e = r[i];
        int slot = atomicAdd(&lcur[e.x - (unsigned)nbase], 1);
        lcol[slot] = (int)e.y;
    }
    __syncthreads();
    for (int i = t; i < cnt; i += 256) col[cbase + i] = lcol[i];

    // ---- counting sort by degree -> perm (bucket-local) ----
    hist[t] = 0;
    __syncthreads();
    int b0 = -1, rk0 = 0, b1 = -1, rk1 = 0;
    if (t < nn) { b0 = min(c0, 255); rk0 = atomicAdd(&hist[b0], 1); }
    if (t + 256 < nn) { b1 = min(c1, 255); rk1 = atomicAdd(&hist[b1], 1); }
    __syncthreads();
    int hv = hist[t];
    sg[t] = hv;
    __syncthreads();
    for (int o = 1; o < 256; o <<= 1) {
        int a = (t >= o) ? sg[t - o] : 0;
        __syncthreads();
        sg[t] += a;
        __syncthreads();
    }
    int hb = sg[t] - hv;
    __syncthreads();
    sg[t] = hb;
    __syncthreads();
    if (t < nn) perm[nbase + sg[b0] + rk0] = nbase + t;
    if (t + 256 < nn) perm[nbase + sg[b1] + rk1] = nbase + t + 256;
}

// ---------------- Generic fused layer, f16 in/out, 8-deep gather, perm-ordered ----------------
// TB threads; WPN = DIN/8 lanes per node; NPB = TB/WPN nodes share one LDS W tile.
// Nodes taken in degree-sorted perm order -> degree-uniform waves/blocks.

template <int DIN, int DOUT, int TB>
__global__ __launch_bounds__(TB) void sage_f16(const uint4* __restrict__ hin,
                                               const int* __restrict__ rp,
                                               const int* __restrict__ col,
                                               const int* __restrict__ perm,
                                               const float* __restrict__ W,
                                               const float* __restrict__ bias,
                                               unsigned int* __restrict__ hout,
                                               int real_din, int n) {
    constexpr int WPN = DIN / 8;
    constexpr int NPB = TB / WPN;
    constexpr int OPT = DOUT / WPN;
    __shared__ float sW[DIN * DOUT];
    __shared__ float sB[DOUT];
    __shared__ float sH[NPB][DIN + 1];

    int tid = threadIdx.x;
    for (int i = tid; i < DIN * DOUT; i += TB) sW[i] = (i < real_din * DOUT) ? W[i] : 0.f;
    if (tid < DOUT) sB[tid] = bias[tid];

    int sub = tid / WPN;
    int t = tid % WPN;
    int pos = blockIdx.x * NPB + sub;
    int v = (pos < n) ? perm[pos] : -1;

    if (v >= 0) {
        int r0 = rp[v], r1 = rp[v + 1];
        const __half2 z = __float2half2_rn(0.f);
        __half2 acc[4][4];
#pragma unroll
        for (int s = 0; s < 4; ++s)
#pragma unroll
            for (int q = 0; q < 4; ++q) acc[s][q] = z;
        int j = r0;
        for (; j + 8 <= r1; j += 8) {
            uint4 w[8];
#pragma unroll
            for (int k = 0; k < 8; ++k) w[k] = hin[col[j + k] * WPN + t];
#pragma unroll
            for (int k = 0; k < 8; ++k) {
                __half2* a = acc[k & 3];
                a[0] = __hadd2(a[0], u2h(w[k].x));
                a[1] = __hadd2(a[1], u2h(w[k].y));
                a[2] = __hadd2(a[2], u2h(w[k].z));
                a[3] = __hadd2(a[3], u2h(w[k].w));
            }
        }
        for (; j + 4 <= r1; j += 4) {
            uint4 w[4];
#pragma unroll
            for (int k = 0; k < 4; ++k) w[k] = hin[col[j + k] * WPN + t];
#pragma unroll
            for (int k = 0; k < 4; ++k) {
                __half2* a = acc[k];
                a[0] = __hadd2(a[0], u2h(w[k].x));
                a[1] = __hadd2(a[1], u2h(w[k].y));
                a[2] = __hadd2(a[2], u2h(w[k].z));
                a[3] = __hadd2(a[3], u2h(w[k].w));
            }
        }
        for (; j < r1; ++j) {
            uint4 w = hin[col[j] * WPN + t];
            acc[0][0] = __hadd2(acc[0][0], u2h(w.x));
            acc[0][1] = __hadd2(acc[0][1], u2h(w.y));
            acc[0][2] = __hadd2(acc[0][2], u2h(w.z));
            acc[0][3] = __hadd2(acc[0][3], u2h(w.w));
        }
#pragma unroll
        for (int q = 0; q < 4; ++q)
            acc[0][q] = __hadd2(__hadd2(acc[0][q], acc[1][q]),
                                __hadd2(acc[2][q], acc[3][q]));
        uint4 ws = hin[v * WPN + t];
        unsigned swd[4] = {ws.x, ws.y, ws.z, ws.w};
        float inv = 1.0f / (float)(r1 - r0 + 1);
#pragma unroll
        for (int q = 0; q < 4; ++q) {
            float2 f = __half22float2(acc[0][q]);
            float2 s = u2f2(swd[q]);
            sH[sub][t * 8 + 2 * q + 0] = (f.x + s.x) * inv;
            sH[sub][t * 8 + 2 * q + 1] = (f.y + s.y) * inv;
        }
    }
    __syncthreads();
    if (v >= 0) {
        int o0 = t * OPT;
        float accO[OPT];
#pragma unroll
        for (int i = 0; i < OPT; ++i) accO[i] = sB[o0 + i];
#pragma unroll 4
        for (int k = 0; k < DIN; ++k) {
            float hk = sH[sub][k];
#pragma unroll
            for (int i = 0; i < OPT; ++i) accO[i] += hk * sW[k * DOUT + o0 + i];
        }
        unsigned wds[OPT / 2];
#pragma unroll
        for (int i = 0; i < OPT; i += 2)
            wds[i / 2] = packh2(fmaxf(accO[i], 0.f), fmaxf(accO[i + 1], 0.f));
        unsigned* op = hout + v * (DOUT / 2) + o0 / 2;
        if constexpr (OPT / 2 == 4) {
            *reinterpret_cast<uint4*>(op) = make_uint4(wds[0], wds[1], wds[2], wds[3]);
        } else if constexpr (OPT / 2 == 8) {
            reinterpret_cast<uint4*>(op)[0] = make_uint4(wds[0], wds[1], wds[2], wds[3]);
            reinterpret_cast<uint4*>(op)[1] = make_uint4(wds[4], wds[5], wds[6], wds[7]);
        } else {
            *reinterpret_cast<uint2*>(op) = make_uint2(wds[0], wds[1]);
        }
    }
}

// ---------------- Pooling: per-graph mean, f16 input ----------------

__device__ __forceinline__ int lower_bound_i(const int* __restrict__ a, int n, int key) {
    int lo = 0, hi = n;
    while (lo < hi) {
        int m = (lo + hi) >> 1;
        if (a[m] < key) lo = m + 1; else hi = m;
    }
    return lo;
}

__global__ __launch_bounds__(256) void pool_f16(const unsigned int* __restrict__ h32,
                                                const int* __restrict__ gids,
                                                float* __restrict__ out, int n) {
    int bx = blockIdx.x;
    int g = bx >> 3, s = bx & 7;
    int start = lower_bound_i(gids, n, g);
    int end = lower_bound_i(gids, n, g + 1);
    int len = end - start;
    float inv = 1.0f / (float)(len > 0 ? len : 1);
    int chunk = (len + 7) / 8;
    int s0 = start + s * chunk;
    int s1 = min(s0 + chunk, end);
    int t = threadIdx.x;
    int d = t & 31, j = t >> 5;
    float a0 = 0.f, a1 = 0.f;
    for (int i = s0 + j; i < s1; i += 8) {
        float2 f = u2f2(h32[(size_t)i * 32 + d]);
        a0 += f.x;
        a1 += f.y;
    }
    __shared__ float red[8][32][2];
    red[j][d][0] = a0;
    red[j][d][1] = a1;
    __syncthreads();
    if (t < 64) {
        int dd = t & 31, e = t >> 5;
        float tot = 0.f;
#pragma unroll
        for (int k = 0; k < 8; ++k) tot += red[k][dd][e];
        atomicAdd(&out[g * 64 + 2 * dd + e], tot * inv);
    }
}

// ---------------- launch ----------------

extern "C" void kernel_launch(void* const* d_in, const int* in_sizes, int n_in,
                              void* d_out, int out_size, void* d_ws, size_t ws_size,
                              hipStream_t stream) {
    const int N = N_NODES, E = N_EDGES;
    const float* feat = (const float*)d_in[0];
    const int* src = (const int*)d_in[1];
    const int* dst = (const int*)d_in[2];
    const int* gids = (const int*)d_in[3];
    const float* W1 = (const float*)d_in[4];
    const float* b1 = (const float*)d_in[5];
    const float* W2 = (const float*)d_in[6];
    const float* b2 = (const float*)d_in[7];
    const float* W3 = (const float*)d_in[8];
    const float* b3 = (const float*)d_in[9];
    const float* W4 = (const float*)d_in[10];
    const float* b4 = (const float*)d_in[11];
    float* out = (float*)d_out;

    // workspace layout
    int* rp = (int*)d_ws;                       // N+1
    int* gcur = rp + (N + 1);                   // 256 bucket cursors
    int* perm = gcur + 256;                     // N (degree-sorted node order)
    int* col = perm + N;                        // E
    size_t off = (size_t)((char*)(col + E) - (char*)d_ws);
    off = (off + 255) & ~(size_t)255;
    unsigned int* h1 = (unsigned int*)((char*)d_ws + off);   // f16 N*16 (N*8 words)
    unsigned int* h2 = h1 + (size_t)N * 8;                   // f16 N*32 (N*16 words)
    unsigned int* h3 = h2 + (size_t)N * 16;                  // f16 N*64 (N*32 words)
    unsigned int* h4 = h3 + (size_t)N * 32;                  // f16 N*64 (N*32 words)
    uint4* feat16 = (uint4*)(h4 + (size_t)N * 32);           // f16 N*8 padded rows (1.6MB)
    // rec: 256*BKT_CAP uint2 = 14.7MB, aliases h3 + start of h4 (dead until layers 3/4)
    uint2* rec = (uint2*)h3;

    hipMemsetAsync(out, 0, (size_t)N_GRAPHS * 64 * sizeof(float), stream);
    hipMemsetAsync(gcur, 0, 256 * sizeof(int), stream);

    prep<<<NBLK_FEAT + NBLK_BIN, 256, 0, stream>>>(feat, dst, src, feat16, gcur, rec, N, E);
    fill_bucket<<<NB_BKT, 256, 0, stream>>>(rec, gcur, rp, col, perm, N);

    // layer1: DIN=8 (6 real) WPN=1 NPB=256, 256 thr
    sage_f16<8, 16, 256><<<(N + 255) / 256, 256, 0, stream>>>(
        feat16, rp, col, perm, W1, b1, h1, 6, N);
    // layer2: DIN=16 WPN=2 NPB=256, 512 thr
    sage_f16<16, 32, 512><<<(N + 255) / 256, 512, 0, stream>>>(
        (const uint4*)h1, rp, col, perm, W2, b2, h2, 16, N);
    // layer3: DIN=32 WPN=4 NPB=128, 512 thr
    sage_f16<32, 64, 512><<<(N + 127) / 128, 512, 0, stream>>>(
        (const uint4*)h2, rp, col, perm, W3, b3, h3, 32, N);
    // layer4: DIN=64 WPN=8 NPB=64, 512 thr
    sage_f16<64, 64, 512><<<(N + 63) / 64, 512, 0, stream>>>(
        (const uint4*)h3, rp, col, perm, W4, b4, h4, 64, N);

    pool_f16<<<N_GRAPHS * 8, 256, 0, stream>>>(h4, gids, out, N);
}

// Round 13
// 174.394 us; speedup vs baseline: 1.0959x; 1.0959x over previous
//
#include <hip/hip_runtime.h>
#include <hip/hip_bf16.h>
#include <hip/hip_fp16.h>

#define N_NODES 100000
#define N_EDGES 1600000
#define N_GRAPHS 64

#define NB_BKT 256      // node buckets for CSR build
#define NPBKT 391       // nodes per bucket (255*391=99705, last bucket 295)
#define EPB 2048        // edges per bin block
#define NBLK_BIN ((N_EDGES + EPB - 1) / EPB)  // 782

// ---------------- f16 helpers ----------------

__device__ __forceinline__ __half2 u2h(unsigned int u) {
    return __builtin_bit_cast(__half2, u);
}
__device__ __forceinline__ float2 u2f2(unsigned int u) {
    return __half22float2(u2h(u));
}
__device__ __forceinline__ unsigned int packh2(float a, float b) {
    return __builtin_bit_cast(unsigned int, __float22half2_rn(make_float2(a, b)));
}

// ---------------- CSR build: bucket-binned, LDS-staged, no global atomics ----------------

__global__ __launch_bounds__(256) void bin_count(const int* __restrict__ dst,
                                                 int* __restrict__ cntmat, int E) {
    __shared__ int cnt[NB_BKT];
    int t = threadIdx.x;
    int e0 = blockIdx.x * EPB;
    cnt[t] = 0;
    __syncthreads();
#pragma unroll
    for (int k = 0; k < 8; ++k) {
        int e = e0 + k * 256 + t;
        if (e < E) {
            unsigned d = (unsigned)dst[e];
            atomicAdd(&cnt[d / (unsigned)NPBKT], 1);
        }
    }
    __syncthreads();
    cntmat[(size_t)blockIdx.x * NB_BKT + t] = cnt[t];
}

__global__ __launch_bounds__(256) void bin_scan(int* __restrict__ cntmat,
                                                int* __restrict__ gcnt, int nblk) {
    __shared__ int s[256];
    int b = blockIdx.x, t = threadIdx.x;
    int running = 0;
    for (int c0 = 0; c0 < nblk; c0 += 256) {
        int idx = c0 + t;
        int v = (idx < nblk) ? cntmat[(size_t)idx * NB_BKT + b] : 0;
        s[t] = v;
        __syncthreads();
        for (int o = 1; o < 256; o <<= 1) {
            int a = (t >= o) ? s[t - o] : 0;
            __syncthreads();
            s[t] += a;
            __syncthreads();
        }
        if (idx < nblk) cntmat[(size_t)idx * NB_BKT + b] = running + s[t] - v;
        running += s[255];
        __syncthreads();
    }
    if (t == 0) gcnt[b] = running;
}

// Regroup edges by bucket in LDS, write records bucket-contiguous.
// colbase computed in-block from gcnt (256-entry LDS scan). stage_b[] records
// each staged slot's bucket at scatter time -> no per-edge binary search.
__global__ __launch_bounds__(256) void bin_write(const int* __restrict__ dst,
                                                 const int* __restrict__ src,
                                                 const int* __restrict__ cntmat,
                                                 const int* __restrict__ gcnt,
                                                 uint2* __restrict__ rec, int E) {
    __shared__ int cnt[NB_BKT];
    __shared__ int lbase[NB_BKT];
    __shared__ int gofs[NB_BKT];
    __shared__ uint2 stage[EPB];
    __shared__ unsigned char stage_b[EPB];
    int t = threadIdx.x;
    int e0 = blockIdx.x * EPB;
    // inline exclusive scan of gcnt -> colbase
    int g = gcnt[t];
    lbase[t] = g;
    __syncthreads();
    for (int o = 1; o < 256; o <<= 1) {
        int a = (t >= o) ? lbase[t - o] : 0;
        __syncthreads();
        lbase[t] += a;
        __syncthreads();
    }
    gofs[t] = (lbase[t] - g) + cntmat[(size_t)blockIdx.x * NB_BKT + t];
    cnt[t] = 0;
    __syncthreads();
    int myb[8], mypos[8];
    unsigned myd[8], mys[8];
#pragma unroll
    for (int k = 0; k < 8; ++k) {
        int e = e0 + k * 256 + t;
        if (e < E) {
            unsigned d = (unsigned)dst[e];
            int b = (int)(d / (unsigned)NPBKT);
            myd[k] = d;
            mys[k] = (unsigned)src[e];
            myb[k] = b;
            mypos[k] = atomicAdd(&cnt[b], 1);
        } else {
            myb[k] = -1;
        }
    }
    __syncthreads();
    int c = cnt[t];
    lbase[t] = c;
    __syncthreads();
    for (int o = 1; o < 256; o <<= 1) {
        int a = (t >= o) ? lbase[t - o] : 0;
        __syncthreads();
        lbase[t] += a;
        __syncthreads();
    }
    lbase[t] = lbase[t] - c;
    __syncthreads();
#pragma unroll
    for (int k = 0; k < 8; ++k)
        if (myb[k] >= 0) {
            int slot = lbase[myb[k]] + mypos[k];
            stage[slot] = make_uint2(myd[k], mys[k]);
            stage_b[slot] = (unsigned char)myb[k];
        }
    __syncthreads();
    int total = min(EPB, E - e0);
    for (int i = t; i < total; i += 256) {
        int b = (int)stage_b[i];
        rec[(size_t)gofs[b] + (i - lbase[b])] = stage[i];
    }
}

// One workgroup per bucket: local deg+prefix -> rp; scatter col inside LDS;
// stream out coalesced. colbase computed in-block from gcnt.
__global__ __launch_bounds__(256) void fill_bucket(const uint2* __restrict__ rec,
                                                   const int* __restrict__ gcnt,
                                                   int* __restrict__ rp,
                                                   int* __restrict__ col, int n) {
    __shared__ int sdeg[512];
    __shared__ int lcur[512];
    __shared__ int sg[256];
    __shared__ int lcol[8192];
    int p = blockIdx.x, t = threadIdx.x;
    int nbase = p * NPBKT;
    int nn = min(NPBKT, n - nbase);
    // inline exclusive scan of gcnt -> cbase
    int g = gcnt[t];
    sg[t] = g;
    __syncthreads();
    for (int o = 1; o < 256; o <<= 1) {
        int a = (t >= o) ? sg[t - o] : 0;
        __syncthreads();
        sg[t] += a;
        __syncthreads();
    }
    int ex = sg[t] - g;
    __syncthreads();
    sg[t] = ex;
    __syncthreads();
    int cbase = sg[p];
    int cnt = gcnt[p];
    sdeg[t] = 0;
    sdeg[t + 256] = 0;
    __syncthreads();
    const uint2* r = rec + cbase;
    for (int i = t; i < cnt; i += 256) atomicAdd(&sdeg[r[i].x - (unsigned)nbase], 1);
    __syncthreads();
    int c0 = sdeg[t], c1 = sdeg[t + 256];
    for (int o = 1; o < 512; o <<= 1) {
        int a = (t >= o) ? sdeg[t - o] : 0;
        int b = (t + 256 >= o) ? sdeg[t + 256 - o] : 0;
        __syncthreads();
        sdeg[t] += a;
        sdeg[t + 256] += b;
        __syncthreads();
    }
    int ex0 = sdeg[t] - c0, ex1 = sdeg[t + 256] - c1;
    lcur[t] = ex0;
    lcur[t + 256] = ex1;
    if (t < nn) rp[nbase + t] = cbase + ex0;
    if (t + 256 < nn) rp[nbase + t + 256] = cbase + ex1;
    if (p == NB_BKT - 1 && t == 0) rp[n] = cbase + cnt;
    __syncthreads();
    for (int i = t; i < cnt; i += 256) {
        uint2 e = r[i];
        int slot = atomicAdd(&lcur[e.x - (unsigned)nbase], 1);
        lcol[slot] = (int)e.y;
    }
    __syncthreads();
    for (int i = t; i < cnt; i += 256) col[cbase + i] = lcol[i];
}

// ---------------- Layer 1 (din=6, dout=16): one thread per node, fp32 in, f16 out ----------------

__global__ __launch_bounds__(256) void sage_layer1(const float* __restrict__ feat,
                                                   const int* __restrict__ rp,
                                                   const int* __restrict__ col,
                                                   const float* __restrict__ W,
                                                   const float* __restrict__ bias,
                                                   unsigned int* __restrict__ hout, int n) {
    __shared__ float sW[6 * 16];
    __shared__ float sB[16];
    int tid = threadIdx.x;
    if (tid < 96) sW[tid] = W[tid];
    if (tid < 16) sB[tid] = bias[tid];
    __syncthreads();
    int v = blockIdx.x * 256 + tid;
    if (v >= n) return;
    int r0 = rp[v], r1 = rp[v + 1];
    float acc[6] = {0.f, 0.f, 0.f, 0.f, 0.f, 0.f};
    const float2* f2 = reinterpret_cast<const float2*>(feat);
    int j = r0;
    for (; j + 4 <= r1; j += 4) {
        int u0 = col[j], u1 = col[j + 1], u2 = col[j + 2], u3 = col[j + 3];
        float2 a0 = f2[u0 * 3 + 0], b0 = f2[u0 * 3 + 1], c0 = f2[u0 * 3 + 2];
        float2 a1 = f2[u1 * 3 + 0], b1 = f2[u1 * 3 + 1], c1 = f2[u1 * 3 + 2];
        float2 a2 = f2[u2 * 3 + 0], b2 = f2[u2 * 3 + 1], c2 = f2[u2 * 3 + 2];
        float2 a3 = f2[u3 * 3 + 0], b3 = f2[u3 * 3 + 1], c3 = f2[u3 * 3 + 2];
        acc[0] += (a0.x + a1.x) + (a2.x + a3.x);
        acc[1] += (a0.y + a1.y) + (a2.y + a3.y);
        acc[2] += (b0.x + b1.x) + (b2.x + b3.x);
        acc[3] += (b0.y + b1.y) + (b2.y + b3.y);
        acc[4] += (c0.x + c1.x) + (c2.x + c3.x);
        acc[5] += (c0.y + c1.y) + (c2.y + c3.y);
    }
    for (; j < r1; ++j) {
        int u = col[j];
        float2 a = f2[u * 3 + 0], b = f2[u * 3 + 1], c = f2[u * 3 + 2];
        acc[0] += a.x; acc[1] += a.y;
        acc[2] += b.x; acc[3] += b.y;
        acc[4] += c.x; acc[5] += c.y;
    }
    {
        float2 a = f2[v * 3 + 0], b = f2[v * 3 + 1], c = f2[v * 3 + 2];
        acc[0] += a.x; acc[1] += a.y;
        acc[2] += b.x; acc[3] += b.y;
        acc[4] += c.x; acc[5] += c.y;
    }
    float inv = 1.0f / (float)(r1 - r0 + 1);
#pragma unroll
    for (int k = 0; k < 6; ++k) acc[k] *= inv;
    float outv[16];
#pragma unroll
    for (int o = 0; o < 16; ++o) outv[o] = sB[o];
#pragma unroll
    for (int k = 0; k < 6; ++k) {
#pragma unroll
        for (int o = 0; o < 16; ++o) outv[o] += acc[k] * sW[k * 16 + o];
    }
    unsigned int w[8];
#pragma unroll
    for (int o = 0; o < 16; o += 2)
        w[o / 2] = packh2(fmaxf(outv[o], 0.f), fmaxf(outv[o + 1], 0.f));
    uint4* op = reinterpret_cast<uint4*>(hout + v * 8);
    op[0] = make_uint4(w[0], w[1], w[2], w[3]);
    op[1] = make_uint4(w[4], w[5], w[6], w[7]);
}

// ---------------- Generic fused layer, f16 in/out, 8-deep gather pipeline ----------------
// WPN = DIN/8 lanes per node; each lane loads one uint4 (8 f16) per edge.

template <int DIN, int DOUT>
__global__ __launch_bounds__(256) void sage_f16(const uint4* __restrict__ hin,
                                                const int* __restrict__ rp,
                                                const int* __restrict__ col,
                                                const float* __restrict__ W,
                                                const float* __restrict__ bias,
                                                unsigned int* __restrict__ hout, int n) {
    constexpr int WPN = DIN / 8;
    constexpr int NPB = 256 / WPN;
    constexpr int OPT = DOUT / WPN;
    __shared__ float sW[DIN * DOUT];
    __shared__ float sB[DOUT];
    __shared__ float sH[NPB][DIN + 1];

    int tid = threadIdx.x;
    for (int i = tid; i < DIN * DOUT; i += 256) sW[i] = W[i];
    if (tid < DOUT) sB[tid] = bias[tid];

    int sub = tid / WPN;
    int t = tid % WPN;
    int v = blockIdx.x * NPB + sub;

    if (v < n) {
        int r0 = rp[v], r1 = rp[v + 1];
        const __half2 z = __float2half2_rn(0.f);
        __half2 acc[4][4];
#pragma unroll
        for (int s = 0; s < 4; ++s)
#pragma unroll
            for (int q = 0; q < 4; ++q) acc[s][q] = z;
        int j = r0;
        for (; j + 8 <= r1; j += 8) {
            uint4 w[8];
#pragma unroll
            for (int k = 0; k < 8; ++k) w[k] = hin[col[j + k] * WPN + t];
#pragma unroll
            for (int k = 0; k < 8; ++k) {
                __half2* a = acc[k & 3];
                a[0] = __hadd2(a[0], u2h(w[k].x));
                a[1] = __hadd2(a[1], u2h(w[k].y));
                a[2] = __hadd2(a[2], u2h(w[k].z));
                a[3] = __hadd2(a[3], u2h(w[k].w));
            }
        }
        for (; j + 4 <= r1; j += 4) {
            uint4 w[4];
#pragma unroll
            for (int k = 0; k < 4; ++k) w[k] = hin[col[j + k] * WPN + t];
#pragma unroll
            for (int k = 0; k < 4; ++k) {
                __half2* a = acc[k];
                a[0] = __hadd2(a[0], u2h(w[k].x));
                a[1] = __hadd2(a[1], u2h(w[k].y));
                a[2] = __hadd2(a[2], u2h(w[k].z));
                a[3] = __hadd2(a[3], u2h(w[k].w));
            }
        }
        for (; j < r1; ++j) {
            uint4 w = hin[col[j] * WPN + t];
            acc[0][0] = __hadd2(acc[0][0], u2h(w.x));
            acc[0][1] = __hadd2(acc[0][1], u2h(w.y));
            acc[0][2] = __hadd2(acc[0][2], u2h(w.z));
            acc[0][3] = __hadd2(acc[0][3], u2h(w.w));
        }
#pragma unroll
        for (int q = 0; q < 4; ++q)
            acc[0][q] = __hadd2(__hadd2(acc[0][q], acc[1][q]),
                                __hadd2(acc[2][q], acc[3][q]));
        uint4 ws = hin[v * WPN + t];
        unsigned swd[4] = {ws.x, ws.y, ws.z, ws.w};
        float inv = 1.0f / (float)(r1 - r0 + 1);
#pragma unroll
        for (int q = 0; q < 4; ++q) {
            float2 f = __half22float2(acc[0][q]);
            float2 s = u2f2(swd[q]);
            sH[sub][t * 8 + 2 * q + 0] = (f.x + s.x) * inv;
            sH[sub][t * 8 + 2 * q + 1] = (f.y + s.y) * inv;
        }
    }
    __syncthreads();
    if (v < n) {
        int o0 = t * OPT;
        float accO[OPT];
#pragma unroll
        for (int i = 0; i < OPT; ++i) accO[i] = sB[o0 + i];
#pragma unroll 4
        for (int k = 0; k < DIN; ++k) {
            float hk = sH[sub][k];
#pragma unroll
            for (int i = 0; i < OPT; ++i) accO[i] += hk * sW[k * DOUT + o0 + i];
        }
        unsigned wds[OPT / 2];
#pragma unroll
        for (int i = 0; i < OPT; i += 2)
            wds[i / 2] = packh2(fmaxf(accO[i], 0.f), fmaxf(accO[i + 1], 0.f));
        unsigned* op = hout + v * (DOUT / 2) + o0 / 2;
        if constexpr (OPT / 2 == 4) {
            *reinterpret_cast<uint4*>(op) = make_uint4(wds[0], wds[1], wds[2], wds[3]);
        } else if constexpr (OPT / 2 == 8) {
            reinterpret_cast<uint4*>(op)[0] = make_uint4(wds[0], wds[1], wds[2], wds[3]);
            reinterpret_cast<uint4*>(op)[1] = make_uint4(wds[4], wds[5], wds[6], wds[7]);
        } else {
            *reinterpret_cast<uint2*>(op) = make_uint2(wds[0], wds[1]);
        }
    }
}

// ---------------- Pooling: per-graph mean, f16 input ----------------

__device__ __forceinline__ int lower_bound_i(const int* __restrict__ a, int n, int key) {
    int lo = 0, hi = n;
    while (lo < hi) {
        int m = (lo + hi) >> 1;
        if (a[m] < key) lo = m + 1; else hi = m;
    }
    return lo;
}

__global__ __launch_bounds__(256) void pool_f16(const unsigned int* __restrict__ h32,
                                                const int* __restrict__ gids,
                                                float* __restrict__ out, int n) {
    int bx = blockIdx.x;
    int g = bx >> 3, s = bx & 7;
    int start = lower_bound_i(gids, n, g);
    int end = lower_bound_i(gids, n, g + 1);
    int len = end - start;
    float inv = 1.0f / (float)(len > 0 ? len : 1);
    int chunk = (len + 7) / 8;
    int s0 = start + s * chunk;
    int s1 = min(s0 + chunk, end);
    int t = threadIdx.x;
    int d = t & 31, j = t >> 5;
    float a0 = 0.f, a1 = 0.f;
    for (int i = s0 + j; i < s1; i += 8) {
        float2 f = u2f2(h32[(size_t)i * 32 + d]);
        a0 += f.x;
        a1 += f.y;
    }
    __shared__ float red[8][32][2];
    red[j][d][0] = a0;
    red[j][d][1] = a1;
    __syncthreads();
    if (t < 64) {
        int dd = t & 31, e = t >> 5;
        float tot = 0.f;
#pragma unroll
        for (int k = 0; k < 8; ++k) tot += red[k][dd][e];
        atomicAdd(&out[g * 64 + 2 * dd + e], tot * inv);
    }
}

// ---------------- launch ----------------

extern "C" void kernel_launch(void* const* d_in, const int* in_sizes, int n_in,
                              void* d_out, int out_size, void* d_ws, size_t ws_size,
                              hipStream_t stream) {
    const int N = N_NODES, E = N_EDGES;
    const float* feat = (const float*)d_in[0];
    const int* src = (const int*)d_in[1];
    const int* dst = (const int*)d_in[2];
    const int* gids = (const int*)d_in[3];
    const float* W1 = (const float*)d_in[4];
    const float* b1 = (const float*)d_in[5];
    const float* W2 = (const float*)d_in[6];
    const float* b2 = (const float*)d_in[7];
    const float* W3 = (const float*)d_in[8];
    const float* b3 = (const float*)d_in[9];
    const float* W4 = (const float*)d_in[10];
    const float* b4 = (const float*)d_in[11];
    float* out = (float*)d_out;

    // workspace layout
    int* rp = (int*)d_ws;                       // N+1
    int* gcnt = rp + (N + 1);                   // 256
    int* cntmat = gcnt + 256;                   // NBLK_BIN*256
    int* col = cntmat + (size_t)NBLK_BIN * 256; // E
    size_t off = (size_t)((char*)(col + E) - (char*)d_ws);
    off = (off + 255) & ~(size_t)255;
    unsigned int* h1 = (unsigned int*)((char*)d_ws + off);   // f16 N*16 (N*8 words)
    unsigned int* h2 = h1 + (size_t)N * 8;                   // f16 N*32 (N*16 words)
    unsigned int* h3 = h2 + (size_t)N * 16;                  // f16 N*64 (N*32 words)
    unsigned int* h4 = h3 + (size_t)N * 32;                  // f16 N*64 (N*32 words)
    uint2* rec = (uint2*)h3;  // E uint2 = 12.8MB edge records; dead before layer-3 writes h3

    hipMemsetAsync(out, 0, (size_t)N_GRAPHS * 64 * sizeof(float), stream);

    bin_count<<<NBLK_BIN, 256, 0, stream>>>(dst, cntmat, E);
    bin_scan<<<NB_BKT, 256, 0, stream>>>(cntmat, gcnt, NBLK_BIN);
    bin_write<<<NBLK_BIN, 256, 0, stream>>>(dst, src, cntmat, gcnt, rec, E);
    fill_bucket<<<NB_BKT, 256, 0, stream>>>(rec, gcnt, rp, col, N);

    sage_layer1<<<(N + 255) / 256, 256, 0, stream>>>(feat, rp, col, W1, b1, h1, N);
    // layer2: DIN=16 WPN=2 NPB=128
    sage_f16<16, 32><<<(N + 127) / 128, 256, 0, stream>>>(
        (const uint4*)h1, rp, col, W2, b2, h2, N);
    // layer3: DIN=32 WPN=4 NPB=64
    sage_f16<32, 64><<<(N + 63) / 64, 256, 0, stream>>>(
        (const uint4*)h2, rp, col, W3, b3, h3, N);
    // layer4: DIN=64 WPN=8 NPB=32
    sage_f16<64, 64><<<(N + 31) / 32, 256, 0, stream>>>(
        (const uint4*)h3, rp, col, W4, b4, h4, N);

    pool_f16<<<N_GRAPHS * 8, 256, 0, stream>>>(h4, gids, out, N);
}

// Round 14
// 168.357 us; speedup vs baseline: 1.1352x; 1.0359x over previous
//
#include <hip/hip_runtime.h>
#include <hip/hip_bf16.h>
#include <hip/hip_fp16.h>

#define N_NODES 100000
#define N_EDGES 1600000
#define N_GRAPHS 64

#define NB_BKT 256      // node buckets for CSR build
#define NPBKT 391       // nodes per bucket (255*391=99705, last bucket 295)
#define EPB 4096        // edges per bin block
#define NBLK_BIN ((N_EDGES + EPB - 1) / EPB)  // 391

// ---------------- f16 helpers ----------------

__device__ __forceinline__ __half2 u2h(unsigned int u) {
    return __builtin_bit_cast(__half2, u);
}
__device__ __forceinline__ float2 u2f2(unsigned int u) {
    return __half22float2(u2h(u));
}
__device__ __forceinline__ unsigned int packh2(float a, float b) {
    return __builtin_bit_cast(unsigned int, __float22half2_rn(make_float2(a, b)));
}

// ---------------- CSR build: bucket-binned, LDS-staged, no global atomics ----------------

__global__ __launch_bounds__(256) void bin_count(const int* __restrict__ dst,
                                                 int* __restrict__ cntmat, int E) {
    __shared__ int cnt[NB_BKT];
    int t = threadIdx.x;
    int e0 = blockIdx.x * EPB;
    cnt[t] = 0;
    __syncthreads();
#pragma unroll
    for (int k = 0; k < 16; ++k) {
        int e = e0 + k * 256 + t;
        if (e < E) {
            unsigned d = (unsigned)dst[e];
            atomicAdd(&cnt[d / (unsigned)NPBKT], 1);
        }
    }
    __syncthreads();
    cntmat[(size_t)blockIdx.x * NB_BKT + t] = cnt[t];
}

__global__ __launch_bounds__(256) void bin_scan(int* __restrict__ cntmat,
                                                int* __restrict__ gcnt, int nblk) {
    __shared__ int s[256];
    int b = blockIdx.x, t = threadIdx.x;
    int running = 0;
    for (int c0 = 0; c0 < nblk; c0 += 256) {
        int idx = c0 + t;
        int v = (idx < nblk) ? cntmat[(size_t)idx * NB_BKT + b] : 0;
        s[t] = v;
        __syncthreads();
        for (int o = 1; o < 256; o <<= 1) {
            int a = (t >= o) ? s[t - o] : 0;
            __syncthreads();
            s[t] += a;
            __syncthreads();
        }
        if (idx < nblk) cntmat[(size_t)idx * NB_BKT + b] = running + s[t] - v;
        running += s[255];
        __syncthreads();
    }
    if (t == 0) gcnt[b] = running;
}

// Regroup edges by bucket in LDS, write records bucket-contiguous.
// colbase computed in-block from gcnt (256-entry LDS scan). stage_b[] records
// each staged slot's bucket at scatter time -> no per-edge binary search.
__global__ __launch_bounds__(256) void bin_write(const int* __restrict__ dst,
                                                 const int* __restrict__ src,
                                                 const int* __restrict__ cntmat,
                                                 const int* __restrict__ gcnt,
                                                 uint2* __restrict__ rec, int E) {
    __shared__ int cnt[NB_BKT];
    __shared__ int lbase[NB_BKT];
    __shared__ int gofs[NB_BKT];
    __shared__ uint2 stage[EPB];           // 32 KB
    __shared__ unsigned char stage_b[EPB]; // 4 KB
    int t = threadIdx.x;
    int e0 = blockIdx.x * EPB;
    // inline exclusive scan of gcnt -> colbase
    int g = gcnt[t];
    lbase[t] = g;
    __syncthreads();
    for (int o = 1; o < 256; o <<= 1) {
        int a = (t >= o) ? lbase[t - o] : 0;
        __syncthreads();
        lbase[t] += a;
        __syncthreads();
    }
    gofs[t] = (lbase[t] - g) + cntmat[(size_t)blockIdx.x * NB_BKT + t];
    cnt[t] = 0;
    __syncthreads();
    int myb[16], mypos[16];
    unsigned myd[16], mys[16];
#pragma unroll
    for (int k = 0; k < 16; ++k) {
        int e = e0 + k * 256 + t;
        if (e < E) {
            unsigned d = (unsigned)dst[e];
            int b = (int)(d / (unsigned)NPBKT);
            myd[k] = d;
            mys[k] = (unsigned)src[e];
            myb[k] = b;
            mypos[k] = atomicAdd(&cnt[b], 1);
        } else {
            myb[k] = -1;
        }
    }
    __syncthreads();
    int c = cnt[t];
    lbase[t] = c;
    __syncthreads();
    for (int o = 1; o < 256; o <<= 1) {
        int a = (t >= o) ? lbase[t - o] : 0;
        __syncthreads();
        lbase[t] += a;
        __syncthreads();
    }
    lbase[t] = lbase[t] - c;
    __syncthreads();
#pragma unroll
    for (int k = 0; k < 16; ++k)
        if (myb[k] >= 0) {
            int slot = lbase[myb[k]] + mypos[k];
            stage[slot] = make_uint2(myd[k], mys[k]);
            stage_b[slot] = (unsigned char)myb[k];
        }
    __syncthreads();
    int total = min(EPB, E - e0);
    for (int i = t; i < total; i += 256) {
        int b = (int)stage_b[i];
        rec[(size_t)gofs[b] + (i - lbase[b])] = stage[i];
    }
}

// One workgroup (512 thr = 8 waves) per bucket: local deg+prefix -> rp; scatter
// col inside LDS; stream out coalesced. colbase computed in-block from gcnt.
__global__ __launch_bounds__(512) void fill_bucket(const uint2* __restrict__ rec,
                                                   const int* __restrict__ gcnt,
                                                   int* __restrict__ rp,
                                                   int* __restrict__ col, int n) {
    __shared__ int sdeg[512];
    __shared__ int lcur[512];
    __shared__ int sg[256];
    __shared__ int lcol[8192];
    int p = blockIdx.x, t = threadIdx.x;
    int nbase = p * NPBKT;
    int nn = min(NPBKT, n - nbase);
    // inline exclusive scan of gcnt (256 entries; threads >=256 idle but convergent)
    int g = (t < 256) ? gcnt[t] : 0;
    if (t < 256) sg[t] = g;
    __syncthreads();
    for (int o = 1; o < 256; o <<= 1) {
        int a = (t >= o && t < 256) ? sg[t - o] : 0;
        __syncthreads();
        if (t < 256) sg[t] += a;
        __syncthreads();
    }
    int ex = (t < 256) ? sg[t] - g : 0;
    __syncthreads();
    if (t < 256) sg[t] = ex;
    __syncthreads();
    int cbase = sg[p];
    int cnt = gcnt[p];
    sdeg[t] = 0;
    __syncthreads();
    const uint2* r = rec + cbase;
    for (int i = t; i < cnt; i += 512) atomicAdd(&sdeg[r[i].x - (unsigned)nbase], 1);
    __syncthreads();
    int c0 = sdeg[t];
    for (int o = 1; o < 512; o <<= 1) {
        int a = (t >= o) ? sdeg[t - o] : 0;
        __syncthreads();
        sdeg[t] += a;
        __syncthreads();
    }
    int ex0 = sdeg[t] - c0;
    lcur[t] = ex0;
    if (t < nn) rp[nbase + t] = cbase + ex0;
    if (p == NB_BKT - 1 && t == 0) rp[n] = cbase + cnt;
    __syncthreads();
    for (int i = t; i < cnt; i += 512) {
        uint2 e = r[i];
        int slot = atomicAdd(&lcur[e.x - (unsigned)nbase], 1);
        lcol[slot] = (int)e.y;
    }
    __syncthreads();
    for (int i = t; i < cnt; i += 512) col[cbase + i] = lcol[i];
}

// ---------------- Layer 1 (din=6, dout=16): one thread per node, fp32 in, f16 out ----------------

__global__ __launch_bounds__(256) void sage_layer1(const float* __restrict__ feat,
                                                   const int* __restrict__ rp,
                                                   const int* __restrict__ col,
                                                   const float* __restrict__ W,
                                                   const float* __restrict__ bias,
                                                   unsigned int* __restrict__ hout, int n) {
    __shared__ float sW[6 * 16];
    __shared__ float sB[16];
    int tid = threadIdx.x;
    if (tid < 96) sW[tid] = W[tid];
    if (tid < 16) sB[tid] = bias[tid];
    __syncthreads();
    int v = blockIdx.x * 256 + tid;
    if (v >= n) return;
    int r0 = rp[v], r1 = rp[v + 1];
    float acc[6] = {0.f, 0.f, 0.f, 0.f, 0.f, 0.f};
    const float2* f2 = reinterpret_cast<const float2*>(feat);
    int j = r0;
    for (; j + 4 <= r1; j += 4) {
        int u0 = col[j], u1 = col[j + 1], u2 = col[j + 2], u3 = col[j + 3];
        float2 a0 = f2[u0 * 3 + 0], b0 = f2[u0 * 3 + 1], c0 = f2[u0 * 3 + 2];
        float2 a1 = f2[u1 * 3 + 0], b1 = f2[u1 * 3 + 1], c1 = f2[u1 * 3 + 2];
        float2 a2 = f2[u2 * 3 + 0], b2 = f2[u2 * 3 + 1], c2 = f2[u2 * 3 + 2];
        float2 a3 = f2[u3 * 3 + 0], b3 = f2[u3 * 3 + 1], c3 = f2[u3 * 3 + 2];
        acc[0] += (a0.x + a1.x) + (a2.x + a3.x);
        acc[1] += (a0.y + a1.y) + (a2.y + a3.y);
        acc[2] += (b0.x + b1.x) + (b2.x + b3.x);
        acc[3] += (b0.y + b1.y) + (b2.y + b3.y);
        acc[4] += (c0.x + c1.x) + (c2.x + c3.x);
        acc[5] += (c0.y + c1.y) + (c2.y + c3.y);
    }
    for (; j < r1; ++j) {
        int u = col[j];
        float2 a = f2[u * 3 + 0], b = f2[u * 3 + 1], c = f2[u * 3 + 2];
        acc[0] += a.x; acc[1] += a.y;
        acc[2] += b.x; acc[3] += b.y;
        acc[4] += c.x; acc[5] += c.y;
    }
    {
        float2 a = f2[v * 3 + 0], b = f2[v * 3 + 1], c = f2[v * 3 + 2];
        acc[0] += a.x; acc[1] += a.y;
        acc[2] += b.x; acc[3] += b.y;
        acc[4] += c.x; acc[5] += c.y;
    }
    float inv = 1.0f / (float)(r1 - r0 + 1);
#pragma unroll
    for (int k = 0; k < 6; ++k) acc[k] *= inv;
    float outv[16];
#pragma unroll
    for (int o = 0; o < 16; ++o) outv[o] = sB[o];
#pragma unroll
    for (int k = 0; k < 6; ++k) {
#pragma unroll
        for (int o = 0; o < 16; ++o) outv[o] += acc[k] * sW[k * 16 + o];
    }
    unsigned int w[8];
#pragma unroll
    for (int o = 0; o < 16; o += 2)
        w[o / 2] = packh2(fmaxf(outv[o], 0.f), fmaxf(outv[o + 1], 0.f));
    uint4* op = reinterpret_cast<uint4*>(hout + v * 8);
    op[0] = make_uint4(w[0], w[1], w[2], w[3]);
    op[1] = make_uint4(w[4], w[5], w[6], w[7]);
}

// ---------------- Generic fused layer, f16 in/out, 8-deep gather pipeline ----------------
// WPN = DIN/8 lanes per node; each lane loads one uint4 (8 f16) per edge.

template <int DIN, int DOUT>
__global__ __launch_bounds__(256) void sage_f16(const uint4* __restrict__ hin,
                                                const int* __restrict__ rp,
                                                const int* __restrict__ col,
                                                const float* __restrict__ W,
                                                const float* __restrict__ bias,
                                                unsigned int* __restrict__ hout, int n) {
    constexpr int WPN = DIN / 8;
    constexpr int NPB = 256 / WPN;
    constexpr int OPT = DOUT / WPN;
    __shared__ float sW[DIN * DOUT];
    __shared__ float sB[DOUT];
    __shared__ float sH[NPB][DIN + 1];

    int tid = threadIdx.x;
    for (int i = tid; i < DIN * DOUT; i += 256) sW[i] = W[i];
    if (tid < DOUT) sB[tid] = bias[tid];

    int sub = tid / WPN;
    int t = tid % WPN;
    int v = blockIdx.x * NPB + sub;

    if (v < n) {
        int r0 = rp[v], r1 = rp[v + 1];
        const __half2 z = __float2half2_rn(0.f);
        __half2 acc[4][4];
#pragma unroll
        for (int s = 0; s < 4; ++s)
#pragma unroll
            for (int q = 0; q < 4; ++q) acc[s][q] = z;
        int j = r0;
        for (; j + 8 <= r1; j += 8) {
            uint4 w[8];
#pragma unroll
            for (int k = 0; k < 8; ++k) w[k] = hin[col[j + k] * WPN + t];
#pragma unroll
            for (int k = 0; k < 8; ++k) {
                __half2* a = acc[k & 3];
                a[0] = __hadd2(a[0], u2h(w[k].x));
                a[1] = __hadd2(a[1], u2h(w[k].y));
                a[2] = __hadd2(a[2], u2h(w[k].z));
                a[3] = __hadd2(a[3], u2h(w[k].w));
            }
        }
        for (; j + 4 <= r1; j += 4) {
            uint4 w[4];
#pragma unroll
            for (int k = 0; k < 4; ++k) w[k] = hin[col[j + k] * WPN + t];
#pragma unroll
            for (int k = 0; k < 4; ++k) {
                __half2* a = acc[k];
                a[0] = __hadd2(a[0], u2h(w[k].x));
                a[1] = __hadd2(a[1], u2h(w[k].y));
                a[2] = __hadd2(a[2], u2h(w[k].z));
                a[3] = __hadd2(a[3], u2h(w[k].w));
            }
        }
        for (; j < r1; ++j) {
            uint4 w = hin[col[j] * WPN + t];
            acc[0][0] = __hadd2(acc[0][0], u2h(w.x));
            acc[0][1] = __hadd2(acc[0][1], u2h(w.y));
            acc[0][2] = __hadd2(acc[0][2], u2h(w.z));
            acc[0][3] = __hadd2(acc[0][3], u2h(w.w));
        }
#pragma unroll
        for (int q = 0; q < 4; ++q)
            acc[0][q] = __hadd2(__hadd2(acc[0][q], acc[1][q]),
                                __hadd2(acc[2][q], acc[3][q]));
        uint4 ws = hin[v * WPN + t];
        unsigned swd[4] = {ws.x, ws.y, ws.z, ws.w};
        float inv = 1.0f / (float)(r1 - r0 + 1);
#pragma unroll
        for (int q = 0; q < 4; ++q) {
            float2 f = __half22float2(acc[0][q]);
            float2 s = u2f2(swd[q]);
            sH[sub][t * 8 + 2 * q + 0] = (f.x + s.x) * inv;
            sH[sub][t * 8 + 2 * q + 1] = (f.y + s.y) * inv;
        }
    }
    __syncthreads();
    if (v < n) {
        int o0 = t * OPT;
        float accO[OPT];
#pragma unroll
        for (int i = 0; i < OPT; ++i) accO[i] = sB[o0 + i];
#pragma unroll 4
        for (int k = 0; k < DIN; ++k) {
            float hk = sH[sub][k];
#pragma unroll
            for (int i = 0; i < OPT; ++i) accO[i] += hk * sW[k * DOUT + o0 + i];
        }
        unsigned wds[OPT / 2];
#pragma unroll
        for (int i = 0; i < OPT; i += 2)
            wds[i / 2] = packh2(fmaxf(accO[i], 0.f), fmaxf(accO[i + 1], 0.f));
        unsigned* op = hout + v * (DOUT / 2) + o0 / 2;
        if constexpr (OPT / 2 == 4) {
            *reinterpret_cast<uint4*>(op) = make_uint4(wds[0], wds[1], wds[2], wds[3]);
        } else if constexpr (OPT / 2 == 8) {
            reinterpret_cast<uint4*>(op)[0] = make_uint4(wds[0], wds[1], wds[2], wds[3]);
            reinterpret_cast<uint4*>(op)[1] = make_uint4(wds[4], wds[5], wds[6], wds[7]);
        } else {
            *reinterpret_cast<uint2*>(op) = make_uint2(wds[0], wds[1]);
        }
    }
}

// ---------------- Pooling: per-graph mean, f16 input ----------------

__device__ __forceinline__ int lower_bound_i(const int* __restrict__ a, int n, int key) {
    int lo = 0, hi = n;
    while (lo < hi) {
        int m = (lo + hi) >> 1;
        if (a[m] < key) lo = m + 1; else hi = m;
    }
    return lo;
}

__global__ __launch_bounds__(256) void pool_f16(const unsigned int* __restrict__ h32,
                                                const int* __restrict__ gids,
                                                float* __restrict__ out, int n) {
    int bx = blockIdx.x;
    int g = bx >> 3, s = bx & 7;
    int start = lower_bound_i(gids, n, g);
    int end = lower_bound_i(gids, n, g + 1);
    int len = end - start;
    float inv = 1.0f / (float)(len > 0 ? len : 1);
    int chunk = (len + 7) / 8;
    int s0 = start + s * chunk;
    int s1 = min(s0 + chunk, end);
    int t = threadIdx.x;
    int d = t & 31, j = t >> 5;
    float a0 = 0.f, a1 = 0.f;
    for (int i = s0 + j; i < s1; i += 8) {
        float2 f = u2f2(h32[(size_t)i * 32 + d]);
        a0 += f.x;
        a1 += f.y;
    }
    __shared__ float red[8][32][2];
    red[j][d][0] = a0;
    red[j][d][1] = a1;
    __syncthreads();
    if (t < 64) {
        int dd = t & 31, e = t >> 5;
        float tot = 0.f;
#pragma unroll
        for (int k = 0; k < 8; ++k) tot += red[k][dd][e];
        atomicAdd(&out[g * 64 + 2 * dd + e], tot * inv);
    }
}

// ---------------- launch ----------------

extern "C" void kernel_launch(void* const* d_in, const int* in_sizes, int n_in,
                              void* d_out, int out_size, void* d_ws, size_t ws_size,
                              hipStream_t stream) {
    const int N = N_NODES, E = N_EDGES;
    const float* feat = (const float*)d_in[0];
    const int* src = (const int*)d_in[1];
    const int* dst = (const int*)d_in[2];
    const int* gids = (const int*)d_in[3];
    const float* W1 = (const float*)d_in[4];
    const float* b1 = (const float*)d_in[5];
    const float* W2 = (const float*)d_in[6];
    const float* b2 = (const float*)d_in[7];
    const float* W3 = (const float*)d_in[8];
    const float* b3 = (const float*)d_in[9];
    const float* W4 = (const float*)d_in[10];
    const float* b4 = (const float*)d_in[11];
    float* out = (float*)d_out;

    // workspace layout
    int* rp = (int*)d_ws;                       // N+1
    int* gcnt = rp + (N + 1);                   // 256
    int* cntmat = gcnt + 256;                   // NBLK_BIN*256
    int* col = cntmat + (size_t)NBLK_BIN * 256; // E
    size_t off = (size_t)((char*)(col + E) - (char*)d_ws);
    off = (off + 255) & ~(size_t)255;
    unsigned int* h1 = (unsigned int*)((char*)d_ws + off);   // f16 N*16 (N*8 words)
    unsigned int* h2 = h1 + (size_t)N * 8;                   // f16 N*32 (N*16 words)
    unsigned int* h3 = h2 + (size_t)N * 16;                  // f16 N*64 (N*32 words)
    unsigned int* h4 = h3 + (size_t)N * 32;                  // f16 N*64 (N*32 words)
    uint2* rec = (uint2*)h3;  // E uint2 = 12.8MB edge records; dead before layer-3 writes h3

    hipMemsetAsync(out, 0, (size_t)N_GRAPHS * 64 * sizeof(float), stream);

    bin_count<<<NBLK_BIN, 256, 0, stream>>>(dst, cntmat, E);
    bin_scan<<<NB_BKT, 256, 0, stream>>>(cntmat, gcnt, NBLK_BIN);
    bin_write<<<NBLK_BIN, 256, 0, stream>>>(dst, src, cntmat, gcnt, rec, E);
    fill_bucket<<<NB_BKT, 512, 0, stream>>>(rec, gcnt, rp, col, N);

    sage_layer1<<<(N + 255) / 256, 256, 0, stream>>>(feat, rp, col, W1, b1, h1, N);
    // layer2: DIN=16 WPN=2 NPB=128
    sage_f16<16, 32><<<(N + 127) / 128, 256, 0, stream>>>(
        (const uint4*)h1, rp, col, W2, b2, h2, N);
    // layer3: DIN=32 WPN=4 NPB=64
    sage_f16<32, 64><<<(N + 63) / 64, 256, 0, stream>>>(
        (const uint4*)h2, rp, col, W3, b3, h3, N);
    // layer4: DIN=64 WPN=8 NPB=32
    sage_f16<64, 64><<<(N + 31) / 32, 256, 0, stream>>>(
        (const uint4*)h3, rp, col, W4, b4, h4, N);

    pool_f16<<<N_GRAPHS * 8, 256, 0, stream>>>(h4, gids, out, N);
}

// Round 15
// 167.627 us; speedup vs baseline: 1.1402x; 1.0044x over previous
//
#include <hip/hip_runtime.h>
#include <hip/hip_bf16.h>
#include <hip/hip_fp16.h>

#define N_NODES 100000
#define N_EDGES 1600000
#define N_GRAPHS 64

#define NB_BKT 256      // node buckets for CSR build
#define NPBKT 391       // nodes per bucket (255*391=99705, last bucket 295)
#define EPB 4096        // edges per bin block
#define NBLK_BIN ((N_EDGES + EPB - 1) / EPB)  // 391
#define BKT_CAP 7168    // per-bucket rec capacity: mean 6256, sigma 79 -> +11.5 sigma

// ---------------- f16 helpers ----------------

__device__ __forceinline__ __half2 u2h(unsigned int u) {
    return __builtin_bit_cast(__half2, u);
}
__device__ __forceinline__ float2 u2f2(unsigned int u) {
    return __half22float2(u2h(u));
}
__device__ __forceinline__ unsigned int packh2(float a, float b) {
    return __builtin_bit_cast(unsigned int, __float22half2_rn(make_float2(a, b)));
}

// ---------------- bin_edges: one-pass bucket binning ----------------
// LDS histogram -> one global atomicAdd per (block,bucket) reserves a range in the
// bucket's fixed-capacity region -> LDS regroup (stage_b O(1) lookup) -> full-line
// bucket-contiguous rec writes. Replaces bin_count+bin_scan+bin_write.

__global__ __launch_bounds__(256) void bin_edges(const int* __restrict__ dst,
                                                 const int* __restrict__ src,
                                                 int* __restrict__ gcur,
                                                 uint2* __restrict__ rec, int E) {
    __shared__ int cnt[NB_BKT];
    __shared__ int lbase[NB_BKT];
    __shared__ int gofs[NB_BKT];
    __shared__ uint2 stage[EPB];           // 32 KB
    __shared__ unsigned char stage_b[EPB]; // 4 KB
    int t = threadIdx.x;
    int e0 = blockIdx.x * EPB;
    cnt[t] = 0;
    __syncthreads();
    int myb[16], mypos[16];
    unsigned myd[16], mys[16];
    const int4* dst4 = reinterpret_cast<const int4*>(dst);
    const int4* src4 = reinterpret_cast<const int4*>(src);
#pragma unroll
    for (int k = 0; k < 4; ++k) {
        int e = e0 + (k * 256 + t) * 4;  // E and e0 are multiples of 4 -> group check exact
        if (e < E) {
            int4 d4 = dst4[e >> 2];
            int4 s4 = src4[e >> 2];
            int dd[4] = {d4.x, d4.y, d4.z, d4.w};
            int ss[4] = {s4.x, s4.y, s4.z, s4.w};
#pragma unroll
            for (int j = 0; j < 4; ++j) {
                unsigned d = (unsigned)dd[j];
                int b = (int)(d / (unsigned)NPBKT);
                myd[k * 4 + j] = d;
                mys[k * 4 + j] = (unsigned)ss[j];
                myb[k * 4 + j] = b;
                mypos[k * 4 + j] = atomicAdd(&cnt[b], 1);
            }
        } else {
#pragma unroll
            for (int j = 0; j < 4; ++j) myb[k * 4 + j] = -1;
        }
    }
    __syncthreads();
    int c = cnt[t];
    int res = (c > 0) ? atomicAdd(&gcur[t], c) : 0;  // reserve range in bucket t
    lbase[t] = c;
    __syncthreads();
    for (int o = 1; o < 256; o <<= 1) {
        int a = (t >= o) ? lbase[t - o] : 0;
        __syncthreads();
        lbase[t] += a;
        __syncthreads();
    }
    lbase[t] -= c;  // exclusive prefix for stage layout
    gofs[t] = res;
    __syncthreads();
#pragma unroll
    for (int k = 0; k < 16; ++k)
        if (myb[k] >= 0) {
            int slot = lbase[myb[k]] + mypos[k];
            stage[slot] = make_uint2(myd[k], mys[k]);
            stage_b[slot] = (unsigned char)myb[k];
        }
    __syncthreads();
    int total = min(EPB, E - e0);
    for (int i = t; i < total; i += 256) {
        int b = (int)stage_b[i];
        rec[(size_t)b * BKT_CAP + gofs[b] + (i - lbase[b])] = stage[i];
    }
}

// ---------------- fill_bucket: one workgroup (512 thr) per bucket ----------------
// Local deg+prefix -> rp; scatter col inside LDS; stream out coalesced (dense col).

__global__ __launch_bounds__(512) void fill_bucket(const uint2* __restrict__ rec,
                                                   const int* __restrict__ gcur,
                                                   int* __restrict__ rp,
                                                   int* __restrict__ col, int n) {
    __shared__ int sdeg[512];
    __shared__ int lcur[512];
    __shared__ int sg[256];
    __shared__ int lcol[8192];
    int p = blockIdx.x, t = threadIdx.x;
    int nbase = p * NPBKT;
    int nn = min(NPBKT, n - nbase);
    // inline exclusive scan of gcur -> dense col base (256 entries; extra threads convergent)
    int g = (t < 256) ? gcur[t] : 0;
    if (t < 256) sg[t] = g;
    __syncthreads();
    for (int o = 1; o < 256; o <<= 1) {
        int a = (t >= o && t < 256) ? sg[t - o] : 0;
        __syncthreads();
        if (t < 256) sg[t] += a;
        __syncthreads();
    }
    int ex = (t < 256) ? sg[t] - g : 0;
    __syncthreads();
    if (t < 256) sg[t] = ex;
    __syncthreads();
    int cbase = sg[p];
    int cnt = gcur[p];
    sdeg[t] = 0;
    __syncthreads();
    const uint2* r = rec + (size_t)p * BKT_CAP;
    for (int i = t; i < cnt; i += 512) atomicAdd(&sdeg[r[i].x - (unsigned)nbase], 1);
    __syncthreads();
    int c0 = sdeg[t];
    for (int o = 1; o < 512; o <<= 1) {
        int a = (t >= o) ? sdeg[t - o] : 0;
        __syncthreads();
        sdeg[t] += a;
        __syncthreads();
    }
    int ex0 = sdeg[t] - c0;
    lcur[t] = ex0;
    if (t < nn) rp[nbase + t] = cbase + ex0;
    if (p == NB_BKT - 1 && t == 0) rp[n] = cbase + cnt;
    __syncthreads();
    for (int i = t; i < cnt; i += 512) {
        uint2 e = r[i];
        int slot = atomicAdd(&lcur[e.x - (unsigned)nbase], 1);
        lcol[slot] = (int)e.y;
    }
    __syncthreads();
    for (int i = t; i < cnt; i += 512) col[cbase + i] = lcol[i];
}

// ---------------- Layer 1 (din=6, dout=16): one thread per node, fp32 in, f16 out ----------------

__global__ __launch_bounds__(256) void sage_layer1(const float* __restrict__ feat,
                                                   const int* __restrict__ rp,
                                                   const int* __restrict__ col,
                                                   const float* __restrict__ W,
                                                   const float* __restrict__ bias,
                                                   unsigned int* __restrict__ hout, int n) {
    __shared__ float sW[6 * 16];
    __shared__ float sB[16];
    int tid = threadIdx.x;
    if (tid < 96) sW[tid] = W[tid];
    if (tid < 16) sB[tid] = bias[tid];
    __syncthreads();
    int v = blockIdx.x * 256 + tid;
    if (v >= n) return;
    int r0 = rp[v], r1 = rp[v + 1];
    float acc[6] = {0.f, 0.f, 0.f, 0.f, 0.f, 0.f};
    const float2* f2 = reinterpret_cast<const float2*>(feat);
    int j = r0;
    for (; j + 4 <= r1; j += 4) {
        int u0 = col[j], u1 = col[j + 1], u2 = col[j + 2], u3 = col[j + 3];
        float2 a0 = f2[u0 * 3 + 0], b0 = f2[u0 * 3 + 1], c0 = f2[u0 * 3 + 2];
        float2 a1 = f2[u1 * 3 + 0], b1 = f2[u1 * 3 + 1], c1 = f2[u1 * 3 + 2];
        float2 a2 = f2[u2 * 3 + 0], b2 = f2[u2 * 3 + 1], c2 = f2[u2 * 3 + 2];
        float2 a3 = f2[u3 * 3 + 0], b3 = f2[u3 * 3 + 1], c3 = f2[u3 * 3 + 2];
        acc[0] += (a0.x + a1.x) + (a2.x + a3.x);
        acc[1] += (a0.y + a1.y) + (a2.y + a3.y);
        acc[2] += (b0.x + b1.x) + (b2.x + b3.x);
        acc[3] += (b0.y + b1.y) + (b2.y + b3.y);
        acc[4] += (c0.x + c1.x) + (c2.x + c3.x);
        acc[5] += (c0.y + c1.y) + (c2.y + c3.y);
    }
    for (; j < r1; ++j) {
        int u = col[j];
        float2 a = f2[u * 3 + 0], b = f2[u * 3 + 1], c = f2[u * 3 + 2];
        acc[0] += a.x; acc[1] += a.y;
        acc[2] += b.x; acc[3] += b.y;
        acc[4] += c.x; acc[5] += c.y;
    }
    {
        float2 a = f2[v * 3 + 0], b = f2[v * 3 + 1], c = f2[v * 3 + 2];
        acc[0] += a.x; acc[1] += a.y;
        acc[2] += b.x; acc[3] += b.y;
        acc[4] += c.x; acc[5] += c.y;
    }
    float inv = 1.0f / (float)(r1 - r0 + 1);
#pragma unroll
    for (int k = 0; k < 6; ++k) acc[k] *= inv;
    float outv[16];
#pragma unroll
    for (int o = 0; o < 16; ++o) outv[o] = sB[o];
#pragma unroll
    for (int k = 0; k < 6; ++k) {
#pragma unroll
        for (int o = 0; o < 16; ++o) outv[o] += acc[k] * sW[k * 16 + o];
    }
    unsigned int w[8];
#pragma unroll
    for (int o = 0; o < 16; o += 2)
        w[o / 2] = packh2(fmaxf(outv[o], 0.f), fmaxf(outv[o + 1], 0.f));
    uint4* op = reinterpret_cast<uint4*>(hout + v * 8);
    op[0] = make_uint4(w[0], w[1], w[2], w[3]);
    op[1] = make_uint4(w[4], w[5], w[6], w[7]);
}

// ---------------- Generic fused layer, f16 in/out, 8-deep gather pipeline ----------------
// WPN = DIN/8 lanes per node; each lane loads one uint4 (8 f16) per edge.

template <int DIN, int DOUT>
__global__ __launch_bounds__(256) void sage_f16(const uint4* __restrict__ hin,
                                                const int* __restrict__ rp,
                                                const int* __restrict__ col,
                                                const float* __restrict__ W,
                                                const float* __restrict__ bias,
                                                unsigned int* __restrict__ hout, int n) {
    constexpr int WPN = DIN / 8;
    constexpr int NPB = 256 / WPN;
    constexpr int OPT = DOUT / WPN;
    __shared__ float sW[DIN * DOUT];
    __shared__ float sB[DOUT];
    __shared__ float sH[NPB][DIN + 1];

    int tid = threadIdx.x;
    for (int i = tid; i < DIN * DOUT; i += 256) sW[i] = W[i];
    if (tid < DOUT) sB[tid] = bias[tid];

    int sub = tid / WPN;
    int t = tid % WPN;
    int v = blockIdx.x * NPB + sub;

    if (v < n) {
        int r0 = rp[v], r1 = rp[v + 1];
        const __half2 z = __float2half2_rn(0.f);
        __half2 acc[4][4];
#pragma unroll
        for (int s = 0; s < 4; ++s)
#pragma unroll
            for (int q = 0; q < 4; ++q) acc[s][q] = z;
        int j = r0;
        for (; j + 8 <= r1; j += 8) {
            uint4 w[8];
#pragma unroll
            for (int k = 0; k < 8; ++k) w[k] = hin[col[j + k] * WPN + t];
#pragma unroll
            for (int k = 0; k < 8; ++k) {
                __half2* a = acc[k & 3];
                a[0] = __hadd2(a[0], u2h(w[k].x));
                a[1] = __hadd2(a[1], u2h(w[k].y));
                a[2] = __hadd2(a[2], u2h(w[k].z));
                a[3] = __hadd2(a[3], u2h(w[k].w));
            }
        }
        for (; j + 4 <= r1; j += 4) {
            uint4 w[4];
#pragma unroll
            for (int k = 0; k < 4; ++k) w[k] = hin[col[j + k] * WPN + t];
#pragma unroll
            for (int k = 0; k < 4; ++k) {
                __half2* a = acc[k];
                a[0] = __hadd2(a[0], u2h(w[k].x));
                a[1] = __hadd2(a[1], u2h(w[k].y));
                a[2] = __hadd2(a[2], u2h(w[k].z));
                a[3] = __hadd2(a[3], u2h(w[k].w));
            }
        }
        for (; j < r1; ++j) {
            uint4 w = hin[col[j] * WPN + t];
            acc[0][0] = __hadd2(acc[0][0], u2h(w.x));
            acc[0][1] = __hadd2(acc[0][1], u2h(w.y));
            acc[0][2] = __hadd2(acc[0][2], u2h(w.z));
            acc[0][3] = __hadd2(acc[0][3], u2h(w.w));
        }
#pragma unroll
        for (int q = 0; q < 4; ++q)
            acc[0][q] = __hadd2(__hadd2(acc[0][q], acc[1][q]),
                                __hadd2(acc[2][q], acc[3][q]));
        uint4 ws = hin[v * WPN + t];
        unsigned swd[4] = {ws.x, ws.y, ws.z, ws.w};
        float inv = 1.0f / (float)(r1 - r0 + 1);
#pragma unroll
        for (int q = 0; q < 4; ++q) {
            float2 f = __half22float2(acc[0][q]);
            float2 s = u2f2(swd[q]);
            sH[sub][t * 8 + 2 * q + 0] = (f.x + s.x) * inv;
            sH[sub][t * 8 + 2 * q + 1] = (f.y + s.y) * inv;
        }
    }
    __syncthreads();
    if (v < n) {
        int o0 = t * OPT;
        float accO[OPT];
#pragma unroll
        for (int i = 0; i < OPT; ++i) accO[i] = sB[o0 + i];
#pragma unroll 4
        for (int k = 0; k < DIN; ++k) {
            float hk = sH[sub][k];
#pragma unroll
            for (int i = 0; i < OPT; ++i) accO[i] += hk * sW[k * DOUT + o0 + i];
        }
        unsigned wds[OPT / 2];
#pragma unroll
        for (int i = 0; i < OPT; i += 2)
            wds[i / 2] = packh2(fmaxf(accO[i], 0.f), fmaxf(accO[i + 1], 0.f));
        unsigned* op = hout + v * (DOUT / 2) + o0 / 2;
        if constexpr (OPT / 2 == 4) {
            *reinterpret_cast<uint4*>(op) = make_uint4(wds[0], wds[1], wds[2], wds[3]);
        } else if constexpr (OPT / 2 == 8) {
            reinterpret_cast<uint4*>(op)[0] = make_uint4(wds[0], wds[1], wds[2], wds[3]);
            reinterpret_cast<uint4*>(op)[1] = make_uint4(wds[4], wds[5], wds[6], wds[7]);
        } else {
            *reinterpret_cast<uint2*>(op) = make_uint2(wds[0], wds[1]);
        }
    }
}

// ---------------- Pooling: per-graph mean, f16 input ----------------

__device__ __forceinline__ int lower_bound_i(const int* __restrict__ a, int n, int key) {
    int lo = 0, hi = n;
    while (lo < hi) {
        int m = (lo + hi) >> 1;
        if (a[m] < key) lo = m + 1; else hi = m;
    }
    return lo;
}

__global__ __launch_bounds__(256) void pool_f16(const unsigned int* __restrict__ h32,
                                                const int* __restrict__ gids,
                                                float* __restrict__ out, int n) {
    int bx = blockIdx.x;
    int g = bx >> 3, s = bx & 7;
    int start = lower_bound_i(gids, n, g);
    int end = lower_bound_i(gids, n, g + 1);
    int len = end - start;
    float inv = 1.0f / (float)(len > 0 ? len : 1);
    int chunk = (len + 7) / 8;
    int s0 = start + s * chunk;
    int s1 = min(s0 + chunk, end);
    int t = threadIdx.x;
    int d = t & 31, j = t >> 5;
    float a0 = 0.f, a1 = 0.f;
    for (int i = s0 + j; i < s1; i += 8) {
        float2 f = u2f2(h32[(size_t)i * 32 + d]);
        a0 += f.x;
        a1 += f.y;
    }
    __shared__ float red[8][32][2];
    red[j][d][0] = a0;
    red[j][d][1] = a1;
    __syncthreads();
    if (t < 64) {
        int dd = t & 31, e = t >> 5;
        float tot = 0.f;
#pragma unroll
        for (int k = 0; k < 8; ++k) tot += red[k][dd][e];
        atomicAdd(&out[g * 64 + 2 * dd + e], tot * inv);
    }
}

// ---------------- launch ----------------

extern "C" void kernel_launch(void* const* d_in, const int* in_sizes, int n_in,
                              void* d_out, int out_size, void* d_ws, size_t ws_size,
                              hipStream_t stream) {
    const int N = N_NODES, E = N_EDGES;
    const float* feat = (const float*)d_in[0];
    const int* src = (const int*)d_in[1];
    const int* dst = (const int*)d_in[2];
    const int* gids = (const int*)d_in[3];
    const float* W1 = (const float*)d_in[4];
    const float* b1 = (const float*)d_in[5];
    const float* W2 = (const float*)d_in[6];
    const float* b2 = (const float*)d_in[7];
    const float* W3 = (const float*)d_in[8];
    const float* b3 = (const float*)d_in[9];
    const float* W4 = (const float*)d_in[10];
    const float* b4 = (const float*)d_in[11];
    float* out = (float*)d_out;

    // workspace layout
    int* rp = (int*)d_ws;                       // N+1
    int* gcur = rp + (N + 1);                   // 256 bucket cursors
    int* col = gcur + 256;                      // E
    size_t off = (size_t)((char*)(col + E) - (char*)d_ws);
    off = (off + 255) & ~(size_t)255;
    unsigned int* h1 = (unsigned int*)((char*)d_ws + off);   // f16 N*16 (N*8 words)
    unsigned int* h2 = h1 + (size_t)N * 8;                   // f16 N*32 (N*16 words)
    unsigned int* h3 = h2 + (size_t)N * 16;                  // f16 N*64 (N*32 words)
    unsigned int* h4 = h3 + (size_t)N * 32;                  // f16 N*64 (N*32 words)
    // rec: 256*BKT_CAP uint2 = 14.7 MB, aliases h3 + start of h4 (dead until layer 3)
    uint2* rec = (uint2*)h3;

    hipMemsetAsync(out, 0, (size_t)N_GRAPHS * 64 * sizeof(float), stream);
    hipMemsetAsync(gcur, 0, 256 * sizeof(int), stream);

    bin_edges<<<NBLK_BIN, 256, 0, stream>>>(dst, src, gcur, rec, E);
    fill_bucket<<<NB_BKT, 512, 0, stream>>>(rec, gcur, rp, col, N);

    sage_layer1<<<(N + 255) / 256, 256, 0, stream>>>(feat, rp, col, W1, b1, h1, N);
    // layer2: DIN=16 WPN=2 NPB=128
    sage_f16<16, 32><<<(N + 127) / 128, 256, 0, stream>>>(
        (const uint4*)h1, rp, col, W2, b2, h2, N);
    // layer3: DIN=32 WPN=4 NPB=64
    sage_f16<32, 64><<<(N + 63) / 64, 256, 0, stream>>>(
        (const uint4*)h2, rp, col, W3, b3, h3, N);
    // layer4: DIN=64 WPN=8 NPB=32
    sage_f16<64, 64><<<(N + 31) / 32, 256, 0, stream>>>(
        (const uint4*)h3, rp, col, W4, b4, h4, N);

    pool_f16<<<N_GRAPHS * 8, 256, 0, stream>>>(h4, gids, out, N);
}